// Round 1
// baseline (582.669 us; speedup 1.0000x reference)
//
#include <hip/hip_runtime.h>
#include <math.h>

#define TS   32
#define HALO 5
#define EXT  42   // TS + 2*HALO
#define NP   48   // 16 batch * 3 channels planes

// ---------------- extract normalized 1D kernel from provided 2D kernel ----------------
__global__ __launch_bounds__(64) void k_extract(const float* __restrict__ kern,
                                                float* __restrict__ k1) {
    __shared__ float row[11];
    int t = threadIdx.x;
    if (t < 11) row[t] = kern[5 * 11 + t];   // center row of the 11x11 kernel
    __syncthreads();
    if (t < 11) {
        float s = 0.f;
#pragma unroll
        for (int i = 0; i < 11; ++i) s += row[i];
        k1[t] = row[t] / s;                  // == normalized 1D gaussian
    }
}

// ---------------- 2x2 average pool (both pred and target in one launch) ----------------
__global__ __launch_bounds__(256) void k_pool(const float* __restrict__ pin,
                                              const float* __restrict__ tin,
                                              float* __restrict__ pout,
                                              float* __restrict__ tout,
                                              int Ho, int Wo) {
    int n = NP * Ho * Wo;
    int i = blockIdx.x * 256 + threadIdx.x;
    if (i >= n) return;
    int x    = i % Wo;
    int rest = i / Wo;
    int y    = rest % Ho;
    int pl   = rest / Ho;
    int Wi = Wo * 2;
    size_t base = ((size_t)pl * (Ho * 2) + 2 * (size_t)y) * Wi + 2 * (size_t)x;
    float2 a = *(const float2*)(pin + base);
    float2 b = *(const float2*)(pin + base + Wi);
    pout[i] = 0.25f * ((a.x + a.y) + (b.x + b.y));
    float2 c = *(const float2*)(tin + base);
    float2 d = *(const float2*)(tin + base + Wi);
    tout[i] = 0.25f * ((c.x + c.y) + (d.x + d.y));
}

// ---------------- fused SSIM per scale: blur 5 quantities + l/cs + reduce ----------------
__global__ __launch_bounds__(256) void k_ssim(const float* __restrict__ pred,
                                              const float* __restrict__ targ,
                                              const float* __restrict__ k1g,
                                              double* __restrict__ accum,
                                              int H, int W, int tilesX, int sidx) {
    __shared__ float sp[EXT][EXT + 2];
    __shared__ float st[EXT][EXT + 2];
    __shared__ float hb[5][EXT][TS + 1];
    __shared__ float red[8];

    int tid  = threadIdx.x;
    int tile = blockIdx.x;
    int pl   = blockIdx.y;
    int ty = tile / tilesX, tx = tile % tilesX;
    int y0 = ty * TS, x0 = tx * TS;
    const size_t pbase = (size_t)pl * H * W;

    float w[11];
#pragma unroll
    for (int j = 0; j < 11; ++j) w[j] = k1g[j];

    // ---- stage halo tile (zero-padded => matches conv SAME) ----
    for (int i = tid; i < EXT * EXT; i += 256) {
        int r = i / EXT, c = i % EXT;
        int gy = y0 - HALO + r, gx = x0 - HALO + c;
        float pv = 0.f, tv = 0.f;
        if (gy >= 0 && gy < H && gx >= 0 && gx < W) {
            size_t idx = pbase + (size_t)gy * W + gx;
            pv = pred[idx];
            tv = targ[idx];
        }
        sp[r][c] = pv;
        st[r][c] = tv;
    }
    __syncthreads();

    // ---- horizontal blur of p, t, p^2, t^2, p*t ----
    for (int i = tid; i < EXT * TS; i += 256) {
        int c = i % TS, r = i / TS;
        float ap = 0.f, at = 0.f, app = 0.f, att = 0.f, apt = 0.f;
#pragma unroll
        for (int j = 0; j < 11; ++j) {
            float p = sp[r][c + j];
            float t = st[r][c + j];
            float wj = w[j];
            ap  += wj * p;
            at  += wj * t;
            app += wj * (p * p);
            att += wj * (t * t);
            apt += wj * (p * t);
        }
        hb[0][r][c] = ap;
        hb[1][r][c] = at;
        hb[2][r][c] = app;
        hb[3][r][c] = att;
        hb[4][r][c] = apt;
    }
    __syncthreads();

    // ---- vertical blur + SSIM map + per-thread accumulate ----
    const float C1 = 1e-4f;   // (0.01*1)^2
    const float C2 = 9e-4f;   // (0.03*1)^2
    float lsum = 0.f, csum = 0.f;
    for (int i = tid; i < TS * TS; i += 256) {
        int x = i % TS, y = i / TS;
        float mu1 = 0.f, mu2 = 0.f, epp = 0.f, ett = 0.f, ept = 0.f;
#pragma unroll
        for (int j = 0; j < 11; ++j) {
            float wj = w[j];
            mu1 += wj * hb[0][y + j][x];
            mu2 += wj * hb[1][y + j][x];
            epp += wj * hb[2][y + j][x];
            ett += wj * hb[3][y + j][x];
            ept += wj * hb[4][y + j][x];
        }
        float m11 = mu1 * mu1, m22 = mu2 * mu2, m12 = mu1 * mu2;
        float s1  = fmaxf(epp - m11, 0.f);
        float s2  = fmaxf(ett - m22, 0.f);
        float s12 = ept - m12;
        float l  = (2.f * m12 + C1) / (m11 + m22 + C1);
        float cs = (2.f * s12 + C2) / (s1 + s2 + C2);
        lsum += l;
        csum += cs;
    }

    // ---- wave (64) shuffle reduce, then cross-wave via LDS ----
#pragma unroll
    for (int o = 32; o > 0; o >>= 1) {
        lsum += __shfl_down(lsum, o, 64);
        csum += __shfl_down(csum, o, 64);
    }
    int wave = tid >> 6;
    if ((tid & 63) == 0) { red[wave * 2] = lsum; red[wave * 2 + 1] = csum; }
    __syncthreads();
    if (tid == 0) {
        float bl = red[0] + red[2] + red[4] + red[6];
        float bc = red[1] + red[3] + red[5] + red[7];
        atomicAdd(&accum[2 * sidx],     (double)bl);
        atomicAdd(&accum[2 * sidx + 1], (double)bc);
    }
}

// ---------------- finalize: weighted power product ----------------
__global__ void k_final(const double* __restrict__ accum, float* __restrict__ out) {
    if (threadIdx.x != 0 || blockIdx.x != 0) return;
    const double wts[5] = {0.0448, 0.2856, 0.3001, 0.2363, 0.1333};
    double ms = 1.0;
    int Hs = 512;
    for (int s = 0; s < 5; ++s) {
        double N  = 48.0 * (double)Hs * (double)Hs;
        double l  = accum[2 * s] / N;
        double cs = accum[2 * s + 1] / N;
        if (cs < 1e-8) cs = 1e-8;
        if (s == 4) {
            if (l < 1e-8) l = 1e-8;
            ms *= pow(l, wts[s]) * pow(cs, wts[s]);
        } else {
            ms *= pow(cs, wts[s]);
        }
        Hs >>= 1;
    }
    out[0] = (float)ms;
}

extern "C" void kernel_launch(void* const* d_in, const int* in_sizes, int n_in,
                              void* d_out, int out_size, void* d_ws, size_t ws_size,
                              hipStream_t stream) {
    const float* pred = (const float*)d_in[0];
    const float* targ = (const float*)d_in[1];
    const float* kern = (const float*)d_in[2];
    float* out = (float*)d_out;

    char* ws = (char*)d_ws;
    double* accum = (double*)ws;             // 10 doubles
    float*  k1    = (float*)(ws + 128);      // 11 floats
    size_t off = 256;
    float* p1 = (float*)(ws + off); off += (size_t)NP * 256 * 256 * 4;
    float* t1 = (float*)(ws + off); off += (size_t)NP * 256 * 256 * 4;
    float* p2 = (float*)(ws + off); off += (size_t)NP * 128 * 128 * 4;
    float* t2 = (float*)(ws + off); off += (size_t)NP * 128 * 128 * 4;
    float* p3 = (float*)(ws + off); off += (size_t)NP * 64 * 64 * 4;
    float* t3 = (float*)(ws + off); off += (size_t)NP * 64 * 64 * 4;
    float* p4 = (float*)(ws + off); off += (size_t)NP * 32 * 32 * 4;
    float* t4 = (float*)(ws + off); off += (size_t)NP * 32 * 32 * 4;

    hipMemsetAsync(accum, 0, 128, stream);   // zero the 10 accumulators
    k_extract<<<1, 64, 0, stream>>>(kern, k1);

    // scale 0 (512)
    {
        int H = 512, tX = H / TS;
        k_ssim<<<dim3(tX * tX, NP), 256, 0, stream>>>(pred, targ, k1, accum, H, H, tX, 0);
    }
    // scale 1 (256)
    {
        int Ho = 256, n = NP * Ho * Ho;
        k_pool<<<(n + 255) / 256, 256, 0, stream>>>(pred, targ, p1, t1, Ho, Ho);
        int tX = Ho / TS;
        k_ssim<<<dim3(tX * tX, NP), 256, 0, stream>>>(p1, t1, k1, accum, Ho, Ho, tX, 1);
    }
    // scale 2 (128)
    {
        int Ho = 128, n = NP * Ho * Ho;
        k_pool<<<(n + 255) / 256, 256, 0, stream>>>(p1, t1, p2, t2, Ho, Ho);
        int tX = Ho / TS;
        k_ssim<<<dim3(tX * tX, NP), 256, 0, stream>>>(p2, t2, k1, accum, Ho, Ho, tX, 2);
    }
    // scale 3 (64)
    {
        int Ho = 64, n = NP * Ho * Ho;
        k_pool<<<(n + 255) / 256, 256, 0, stream>>>(p2, t2, p3, t3, Ho, Ho);
        int tX = Ho / TS;
        k_ssim<<<dim3(tX * tX, NP), 256, 0, stream>>>(p3, t3, k1, accum, Ho, Ho, tX, 3);
    }
    // scale 4 (32)
    {
        int Ho = 32, n = NP * Ho * Ho;
        k_pool<<<(n + 255) / 256, 256, 0, stream>>>(p3, t3, p4, t4, Ho, Ho);
        int tX = Ho / TS;
        k_ssim<<<dim3(tX * tX, NP), 256, 0, stream>>>(p4, t4, k1, accum, Ho, Ho, tX, 4);
    }
    k_final<<<1, 1, 0, stream>>>(accum, out);
}

// Round 2
// 334.639 us; speedup vs baseline: 1.7412x; 1.7412x over previous
//
#include <hip/hip_runtime.h>
#include <math.h>

#define NP 48   // 16 batch * 3 channels

// ---------------- extract normalized 1D kernel from provided 2D kernel ----------------
__global__ __launch_bounds__(64) void k_extract(const float* __restrict__ kern,
                                                float* __restrict__ k1) {
    __shared__ float row[11];
    int t = threadIdx.x;
    if (t < 11) row[t] = kern[5 * 11 + t];   // center row of the 11x11 kernel
    __syncthreads();
    if (t < 11) {
        float s = 0.f;
#pragma unroll
        for (int i = 0; i < 11; ++i) s += row[i];
        k1[t] = row[t] / s;                  // == normalized 1D gaussian
    }
}

// ---------------- hierarchical 2x2 pools: s0 -> s1,s2,s3,s4 (pred and targ) ----------------
__global__ __launch_bounds__(256) void k_poolall(
        const float* __restrict__ p0, const float* __restrict__ t0,
        float* __restrict__ p1, float* __restrict__ t1,
        float* __restrict__ p2, float* __restrict__ t2,
        float* __restrict__ p3, float* __restrict__ t3,
        float* __restrict__ p4, float* __restrict__ t4) {
    __shared__ float l1[16][17];
    __shared__ float l2[8][9];
    __shared__ float l3[4][5];
    int t    = threadIdx.x;
    int tile = blockIdx.x;          // 256 tiles: 16x16 grid over the 256x256 s1 plane
    int pl   = blockIdx.y;
    int tY = tile >> 4, tX = tile & 15;

    const float* srcs[2] = {p0, t0};
    float* d1s[2] = {p1, t1};
    float* d2s[2] = {p2, t2};
    float* d3s[2] = {p3, t3};
    float* d4s[2] = {p4, t4};

    for (int a = 0; a < 2; ++a) {
        const float* src = srcs[a];
        // s1: one output per thread
        int ty = t >> 4, tx = t & 15;
        int y1 = tY * 16 + ty, x1 = tX * 16 + tx;
        size_t b0 = (size_t)pl * 512 * 512 + (size_t)(2 * y1) * 512 + 2 * x1;
        float2 r0 = *(const float2*)(src + b0);
        float2 r1 = *(const float2*)(src + b0 + 512);
        float v1 = 0.25f * ((r0.x + r0.y) + (r1.x + r1.y));
        d1s[a][(size_t)pl * 256 * 256 + (size_t)y1 * 256 + x1] = v1;
        l1[ty][tx] = v1;
        __syncthreads();
        if (t < 64) {
            int y = t >> 3, x = t & 7;
            float v2 = 0.25f * (l1[2*y][2*x] + l1[2*y][2*x+1] + l1[2*y+1][2*x] + l1[2*y+1][2*x+1]);
            d2s[a][(size_t)pl * 128 * 128 + (size_t)(tY*8 + y) * 128 + (tX*8 + x)] = v2;
            l2[y][x] = v2;
        }
        __syncthreads();
        if (t < 16) {
            int y = t >> 2, x = t & 3;
            float v3 = 0.25f * (l2[2*y][2*x] + l2[2*y][2*x+1] + l2[2*y+1][2*x] + l2[2*y+1][2*x+1]);
            d3s[a][(size_t)pl * 64 * 64 + (size_t)(tY*4 + y) * 64 + (tX*4 + x)] = v3;
            l3[y][x] = v3;
        }
        __syncthreads();
        if (t < 4) {
            int y = t >> 1, x = t & 1;
            float v4 = 0.25f * (l3[2*y][2*x] + l3[2*y][2*x+1] + l3[2*y+1][2*x] + l3[2*y+1][2*x+1]);
            d4s[a][(size_t)pl * 32 * 32 + (size_t)(tY*2 + y) * 32 + (tX*2 + x)] = v4;
        }
        __syncthreads();
    }
}

// ---------------- fused all-scale SSIM: thread-per-column register sliding window ----------------
// Block ranges: [0,768) s0(H=512,BH=64)  [768,960) s1(256,64)  [960,1056) s2(128,32)
//               [1056,1080) s3(64,32)    [1080,1086) s4(32,32)
__global__ __launch_bounds__(256) void k_ssim_all(
        const float* __restrict__ pred, const float* __restrict__ targ,
        const float* __restrict__ p1, const float* __restrict__ t1,
        const float* __restrict__ p2, const float* __restrict__ t2,
        const float* __restrict__ p3, const float* __restrict__ t3,
        const float* __restrict__ p4, const float* __restrict__ t4,
        const float* __restrict__ k1g, double* __restrict__ accum) {
    int b   = blockIdx.x;
    int tid = threadIdx.x;
    const float *P, *T;
    int H, sh, BH, base, scale;
    if (b < 768)       { scale = 0; H = 512; sh = 9; BH = 64; base = 0;    P = pred; T = targ; }
    else if (b < 960)  { scale = 1; H = 256; sh = 8; BH = 64; base = 768;  P = p1;   T = t1;   }
    else if (b < 1056) { scale = 2; H = 128; sh = 7; BH = 32; base = 960;  P = p2;   T = t2;   }
    else if (b < 1080) { scale = 3; H = 64;  sh = 6; BH = 32; base = 1056; P = p3;   T = t3;   }
    else               { scale = 4; H = 32;  sh = 5; BH = 32; base = 1080; P = p4;   T = t4;   }
    int lb      = b - base;
    int blocksX = (NP << sh) >> 8;          // 48*H / 256
    int bxi = lb % blocksX;
    int by  = lb / blocksX;
    int g   = (bxi << 8) + tid;
    int pl  = g >> sh;
    int x   = g & (H - 1);
    int yb   = by * BH;
    int yend = yb + BH;                     // H is a multiple of BH

    const float* Pp = P + (size_t)pl * H * H;
    const float* Tp = T + (size_t)pl * H * H;

    // per-thread column taps: clamped offsets + edge-zeroed weights
    float w[11], wc[11];
    int coff[11];
#pragma unroll
    for (int j = 0; j < 11; ++j) {
        w[j] = k1g[j];
        int gx = x - 5 + j;
        int cg = gx < 0 ? 0 : (gx > H - 1 ? H - 1 : gx);
        wc[j]  = (gx >= 0 && gx < H) ? w[j] : 0.f;
        coff[j] = cg;
    }

    float wn[5][11];                        // h-blur circular window (registers)
    const float C1 = 1e-4f, C2 = 9e-4f;
    float lsum = 0.f, csum = 0.f;
    int steps  = BH + 10;                   // uniform
    int nchunk = (steps + 10) / 11;
    int r0 = yb - 5;

    for (int ch = 0; ch < nchunk; ++ch) {
#pragma unroll
        for (int ph = 0; ph < 11; ++ph) {
            int rr = r0 + ch * 11 + ph;     // uniform row
            if (rr < yend + 5) {
                float ap = 0.f, at = 0.f, app = 0.f, att = 0.f, apt = 0.f;
                if (rr >= 0 && rr < H) {    // uniform branch
                    const float* prow = Pp + ((size_t)rr << sh);
                    const float* trow = Tp + ((size_t)rr << sh);
#pragma unroll
                    for (int j = 0; j < 11; ++j) {
                        float p  = prow[coff[j]];
                        float t  = trow[coff[j]];
                        float wp = wc[j] * p;
                        float wt = wc[j] * t;
                        ap  += wp;      at  += wt;
                        app += wp * p;  att += wt * t;  apt += wp * t;
                    }
                }
                wn[0][ph] = ap; wn[1][ph] = at; wn[2][ph] = app;
                wn[3][ph] = att; wn[4][ph] = apt;
                if (rr >= yb + 5) {         // uniform: emit output y = rr-5
                    float mu1 = 0.f, mu2 = 0.f, epp = 0.f, ett = 0.f, ept = 0.f;
#pragma unroll
                    for (int i = 0; i < 11; ++i) {
                        const int sl = (ph + 1 + i) % 11;   // compile-time
                        mu1 += w[i] * wn[0][sl];
                        mu2 += w[i] * wn[1][sl];
                        epp += w[i] * wn[2][sl];
                        ett += w[i] * wn[3][sl];
                        ept += w[i] * wn[4][sl];
                    }
                    float m11 = mu1 * mu1, m22 = mu2 * mu2, m12 = mu1 * mu2;
                    float s1  = fmaxf(epp - m11, 0.f);
                    float s2  = fmaxf(ett - m22, 0.f);
                    float s12 = ept - m12;
                    lsum += (2.f * m12 + C1) / (m11 + m22 + C1);
                    csum += (2.f * s12 + C2) / (s1 + s2 + C2);
                }
            }
        }
    }

    // wave shuffle reduce then cross-wave via LDS
#pragma unroll
    for (int o = 32; o > 0; o >>= 1) {
        lsum += __shfl_down(lsum, o, 64);
        csum += __shfl_down(csum, o, 64);
    }
    __shared__ float red[8];
    int wv = tid >> 6;
    if ((tid & 63) == 0) { red[2 * wv] = lsum; red[2 * wv + 1] = csum; }
    __syncthreads();
    if (tid == 0) {
        atomicAdd(&accum[2 * scale],     (double)(red[0] + red[2] + red[4] + red[6]));
        atomicAdd(&accum[2 * scale + 1], (double)(red[1] + red[3] + red[5] + red[7]));
    }
}

// ---------------- finalize: weighted power product ----------------
__global__ void k_final(const double* __restrict__ accum, float* __restrict__ out) {
    if (threadIdx.x != 0 || blockIdx.x != 0) return;
    const double wts[5] = {0.0448, 0.2856, 0.3001, 0.2363, 0.1333};
    double ms = 1.0;
    int Hs = 512;
    for (int s = 0; s < 5; ++s) {
        double N  = 48.0 * (double)Hs * (double)Hs;
        double l  = accum[2 * s] / N;
        double cs = accum[2 * s + 1] / N;
        if (cs < 1e-8) cs = 1e-8;
        if (s == 4) {
            if (l < 1e-8) l = 1e-8;
            ms *= pow(l, wts[s]) * pow(cs, wts[s]);
        } else {
            ms *= pow(cs, wts[s]);
        }
        Hs >>= 1;
    }
    out[0] = (float)ms;
}

extern "C" void kernel_launch(void* const* d_in, const int* in_sizes, int n_in,
                              void* d_out, int out_size, void* d_ws, size_t ws_size,
                              hipStream_t stream) {
    const float* pred = (const float*)d_in[0];
    const float* targ = (const float*)d_in[1];
    const float* kern = (const float*)d_in[2];
    float* out = (float*)d_out;

    char* ws = (char*)d_ws;
    double* accum = (double*)ws;             // 10 doubles
    float*  k1    = (float*)(ws + 128);      // 11 floats
    size_t off = 256;
    float* p1 = (float*)(ws + off); off += (size_t)NP * 256 * 256 * 4;
    float* t1 = (float*)(ws + off); off += (size_t)NP * 256 * 256 * 4;
    float* p2 = (float*)(ws + off); off += (size_t)NP * 128 * 128 * 4;
    float* t2 = (float*)(ws + off); off += (size_t)NP * 128 * 128 * 4;
    float* p3 = (float*)(ws + off); off += (size_t)NP * 64 * 64 * 4;
    float* t3 = (float*)(ws + off); off += (size_t)NP * 64 * 64 * 4;
    float* p4 = (float*)(ws + off); off += (size_t)NP * 32 * 32 * 4;
    float* t4 = (float*)(ws + off); off += (size_t)NP * 32 * 32 * 4;

    hipMemsetAsync(accum, 0, 128, stream);
    k_extract<<<1, 64, 0, stream>>>(kern, k1);
    k_poolall<<<dim3(256, NP), 256, 0, stream>>>(pred, targ, p1, t1, p2, t2, p3, t3, p4, t4);
    k_ssim_all<<<1086, 256, 0, stream>>>(pred, targ, p1, t1, p2, t2, p3, t3, p4, t4, k1, accum);
    k_final<<<1, 1, 0, stream>>>(accum, out);
}